// Round 7
// baseline (105.305 us; speedup 1.0000x reference)
//
#include <hip/hip_runtime.h>

// Problem constants (match reference)
#define NB 8
#define HH 352
#define WW 352
#define RAD 5
#define TX 32
#define TY 16
#define LW (TX + 2*RAD)     // 42
#define LH (TY + 2*RAD)     // 26
#define LSTRIDE 43          // padded row stride in float4 units (odd -> spread banks)
#define TILES_X (WW / TX)   // 11
#define TILES_Y (HH / TY)   // 22
#define NBLK (TILES_X * TILES_Y * NB)  // 1936

// Pre-scale rgb by sqrt(ALPHA * log2(e)) so wgt = exp2(-sum(d^2)):
// sqrt(200 * 1.4426950408889634)
#define RGB_SCALE 16.98644781888824f

typedef float f32x2 __attribute__((ext_vector_type(2)));

// One window element vs a PAIR of centers — packed fp32 (v_pk_*) path.
__device__ __forceinline__ void tap_pair(float wx, float wy, float wz, float ww,
                                         f32x2 cx, f32x2 cy, f32x2 cz, f32x2 cw,
                                         float& accA, float& accB) {
    f32x2 d0 = cx - wx;
    f32x2 d1 = cy - wy;
    f32x2 d2 = cz - wz;
    f32x2 s  = d0 * d0;
    s += d1 * d1;
    s += d2 * d2;
    f32x2 ds = cw - ww;
    accA = fmaf(__builtin_amdgcn_exp2f(-s.x), fabsf(ds.x), accA);
    accB = fmaf(__builtin_amdgcn_exp2f(-s.y), fabsf(ds.y), accB);
}

__device__ __forceinline__ void tap_scalar(const float4& wn, const float4& c,
                                           float& acc) {
    float d0 = wn.x - c.x, d1 = wn.y - c.y, d2 = wn.z - c.z;
    float s = fmaf(d0, d0, fmaf(d1, d1, d2 * d2));
    float e = __builtin_amdgcn_exp2f(-s);   // raw v_exp_f32
    acc = fmaf(e, fabsf(wn.w - c.w), acc);
}

// Separable 5x5 dil-ero mask for 4 x-adjacent pixels.
template <bool INTERIOR>
__device__ __forceinline__ void compute_mask4(const float4* __restrict__ tile,
                                              int ty, int px0, int gy, int gx0,
                                              float* mask) {
    float cmx[8], cmn[8];
    #pragma unroll
    for (int j = 0; j < 8; ++j) {
        int col = px0 + 3 + j;  // tile x of (gx0 - 2 + j)
        float mx = 0.f, mn = 1.f;
        #pragma unroll
        for (int r = 0; r < 5; ++r) {
            float l = (tile[(ty + 3 + r) * LSTRIDE + col].w > 0.5f) ? 1.f : 0.f;
            mx = fmaxf(mx, l);
            if (INTERIOR) {
                mn = fminf(mn, l);
            } else {
                bool rowv = (unsigned)(gy - 2 + r) < (unsigned)HH;
                mn = fminf(mn, rowv ? l : 1.f);
            }
        }
        cmx[j] = mx;
        if (INTERIOR) {
            cmn[j] = mn;
        } else {
            bool colv = (unsigned)(gx0 - 2 + j) < (unsigned)WW;
            cmn[j] = colv ? mn : 1.f;
        }
    }
    #pragma unroll
    for (int k = 0; k < 4; ++k) {
        float mx = cmx[k], mn = cmn[k];
        #pragma unroll
        for (int j2 = 1; j2 < 5; ++j2) {
            mx = fmaxf(mx, cmx[k + j2]);
            mn = fminf(mn, cmn[k + j2]);
        }
        mask[k] = mx - mn;  // 0 or 1
    }
}

// block=256, min 8 waves/EU -> 8 blocks/CU (VGPR<=64, LDS 19968B*8 <= 160KB):
// full 32-wave residency; grid (1936 = 7.6 blocks/CU) becomes fully co-resident.
__global__ __launch_bounds__(256, 8)
void btm_loss_kernel(const float* __restrict__ pred,
                     const float* __restrict__ feat,
                     float2* __restrict__ partials) {
    __shared__ float4 tile[LH * LSTRIDE];  // 26*43*16B = 17.9 KB
    __shared__ float4 xch[128];            // dy-split partial-acc exchange
    __shared__ float2 wred[4];

    int bid = blockIdx.x;
    int tx_blk = bid % TILES_X;
    int ty_blk = (bid / TILES_X) % TILES_Y;
    int n = bid / (TILES_X * TILES_Y);

    const int x0 = tx_blk * TX;
    const int y0 = ty_blk * TY;

    const size_t plane = (size_t)HH * WW;
    const float* fr = feat + ((size_t)n * 3 + 0) * plane;
    const float* fg = feat + ((size_t)n * 3 + 1) * plane;
    const float* fb = feat + ((size_t)n * 3 + 2) * plane;
    const float* ps = pred + (size_t)n * plane;

    // ---- stage tile (zero-padded halo, matching jnp.pad; rgb pre-scaled) ----
    for (int i = threadIdx.x; i < LH * LW; i += 256) {
        int lr = i / LW;
        int lc = i - lr * LW;
        int gy = y0 + lr - RAD;
        int gx = x0 + lc - RAD;
        float4 v = make_float4(0.f, 0.f, 0.f, 0.f);
        if ((unsigned)gy < (unsigned)HH && (unsigned)gx < (unsigned)WW) {
            int gi = gy * WW + gx;
            v.x = fr[gi] * RGB_SCALE;
            v.y = fg[gi] * RGB_SCALE;
            v.z = fb[gi] * RGB_SCALE;
            v.w = ps[gi];
        }
        tile[lr * LSTRIDE + lc] = v;
    }
    __syncthreads();

    // 2 wave-pair groups split the 11 dy rows; each thread owns 4 x-adjacent px.
    const int t   = threadIdx.x;
    const int g   = t >> 7;      // 0: dy 0..5, 1: dy 6..10 (wave-uniform)
    const int tl  = t & 127;
    const int txq = tl & 7;      // 0..7  (x group)
    const int ty  = tl >> 3;     // 0..15 (row)
    const int px0 = txq * 4;

    float4 c0 = tile[(ty + RAD) * LSTRIDE + (px0 + 0 + RAD)];
    float4 c1 = tile[(ty + RAD) * LSTRIDE + (px0 + 1 + RAD)];
    float4 c2 = tile[(ty + RAD) * LSTRIDE + (px0 + 2 + RAD)];
    float4 c3 = tile[(ty + RAD) * LSTRIDE + (px0 + 3 + RAD)];

    // packed center pairs
    f32x2 c01x = {c0.x, c1.x}, c01y = {c0.y, c1.y}, c01z = {c0.z, c1.z}, c01w = {c0.w, c1.w};
    f32x2 c23x = {c2.x, c3.x}, c23y = {c2.y, c3.y}, c23z = {c2.z, c3.z}, c23w = {c2.w, c3.w};

    float acc0 = 0.f, acc1 = 0.f, acc2 = 0.f, acc3 = 0.f;

    const int dy_lo = g ? 6 : 0;
    const int dy_hi = g ? 11 : 6;
    for (int dy = dy_lo; dy < dy_hi; ++dy) {
        const float4* row = &tile[(ty + dy) * LSTRIDE + px0];
        float4 wv[14];
        #pragma unroll
        for (int j = 0; j < 14; ++j) wv[j] = row[j];

        // edge taps (pair halves with non-overlapping valid ranges)
        tap_scalar(wv[0],  c0, acc0);   // c0: dx=0
        tap_scalar(wv[11], c1, acc1);   // c1: dx=10
        tap_scalar(wv[2],  c2, acc2);   // c2: dx=0
        tap_scalar(wv[13], c3, acc3);   // c3: dx=10

        #pragma unroll
        for (int j = 1; j <= 10; ++j)
            tap_pair(wv[j].x, wv[j].y, wv[j].z, wv[j].w,
                     c01x, c01y, c01z, c01w, acc0, acc1);
        #pragma unroll
        for (int j = 3; j <= 12; ++j)
            tap_pair(wv[j].x, wv[j].y, wv[j].z, wv[j].w,
                     c23x, c23y, c23z, c23w, acc2, acc3);
    }

    // ---- exchange: group 1 hands its partial accs to group 0 ----
    if (g == 1) xch[tl] = make_float4(acc0, acc1, acc2, acc3);
    __syncthreads();

    float num = 0.f, den = 0.f;
    if (g == 0) {
        float4 o = xch[tl];
        acc0 += o.x; acc1 += o.y; acc2 += o.z; acc3 += o.w;

        const int gy  = y0 + ty;
        const int gx0 = x0 + px0;
        float mask[4];
        bool interior = (tx_blk >= 1) && (tx_blk <= 9) &&
                        (ty_blk >= 1) && (ty_blk <= 20);
        if (interior) compute_mask4<true >(tile, ty, px0, gy, gx0, mask);
        else          compute_mask4<false>(tile, ty, px0, gy, gx0, mask);

        num = fmaf(mask[0], acc0, fmaf(mask[1], acc1,
              fmaf(mask[2], acc2, mask[3] * acc3)));
        den = ((mask[0] + mask[1]) + (mask[2] + mask[3]));
    }

    // ---- wave reduce -> block reduce -> deterministic partial store ----
    #pragma unroll
    for (int off = 32; off > 0; off >>= 1) {
        num += __shfl_down(num, off, 64);
        den += __shfl_down(den, off, 64);
    }
    int wid  = t >> 6;
    int lane = t & 63;
    if (lane == 0) wred[wid] = make_float2(num, den);
    __syncthreads();
    if (t == 0) {
        float2 a = wred[0];
        a.x += wred[1].x; a.y += wred[1].y;  // waves 2,3 contribute zeros
        partials[bid] = a;
    }
}

__global__ __launch_bounds__(256)
void btm_finalize_kernel(const float2* __restrict__ partials,
                         float* __restrict__ out) {
    __shared__ float2 wred[4];
    float num = 0.f, den = 0.f;
    for (int i = threadIdx.x; i < NBLK; i += 256) {
        float2 p = partials[i];
        num += p.x;
        den += p.y;
    }
    #pragma unroll
    for (int off = 32; off > 0; off >>= 1) {
        num += __shfl_down(num, off, 64);
        den += __shfl_down(den, off, 64);
    }
    int wid  = threadIdx.x >> 6;
    int lane = threadIdx.x & 63;
    if (lane == 0) wred[wid] = make_float2(num, den);
    __syncthreads();
    if (threadIdx.x == 0) {
        float2 a = wred[0];
        #pragma unroll
        for (int w = 1; w < 4; ++w) { a.x += wred[w].x; a.y += wred[w].y; }
        out[0] = a.x / (a.y + 1e-6f);
    }
}

extern "C" void kernel_launch(void* const* d_in, const int* in_sizes, int n_in,
                              void* d_out, int out_size, void* d_ws, size_t ws_size,
                              hipStream_t stream) {
    const float* pred = (const float*)d_in[0];  // (8,1,352,352) fp32
    const float* feat = (const float*)d_in[1];  // (8,3,352,352) fp32
    float* out = (float*)d_out;                 // scalar fp32
    float2* partials = (float2*)d_ws;           // NBLK float2 = 15.5 KB

    btm_loss_kernel<<<dim3(NBLK), dim3(256), 0, stream>>>(pred, feat, partials);
    btm_finalize_kernel<<<dim3(1), dim3(256), 0, stream>>>(partials, out);
}

// Round 8
// 101.753 us; speedup vs baseline: 1.0349x; 1.0349x over previous
//
#include <hip/hip_runtime.h>

// Problem constants (match reference)
#define NB 8
#define HH 352
#define WW 352
#define RAD 5
#define TX 32
#define TY 8
#define LW (TX + 2*RAD)     // 42
#define LH (TY + 2*RAD)     // 18
#define LSTRIDE 43          // padded row stride in float4 units
#define TILES_X (WW / TX)   // 11
#define TILES_Y (HH / TY)   // 44
#define NBLK (TILES_X * TILES_Y * NB)  // 3872

// Pre-scale rgb by sqrt(ALPHA * log2(e)) so wgt = exp2(-sum(d^2)):
#define RGB_SCALE 16.98644781888824f

typedef float f32x2 __attribute__((ext_vector_type(2)));

// One window element vs a PAIR of centers — packed fp32 (v_pk_*) path.
__device__ __forceinline__ void tap_pair(float wx, float wy, float wz, float ww,
                                         f32x2 cx, f32x2 cy, f32x2 cz, f32x2 cw,
                                         float& accA, float& accB) {
    f32x2 d0 = cx - wx;
    f32x2 d1 = cy - wy;
    f32x2 d2 = cz - wz;
    f32x2 s  = d0 * d0;
    s += d1 * d1;
    s += d2 * d2;
    f32x2 ds = cw - ww;
    accA = fmaf(__builtin_amdgcn_exp2f(-s.x), fabsf(ds.x), accA);
    accB = fmaf(__builtin_amdgcn_exp2f(-s.y), fabsf(ds.y), accB);
}

__device__ __forceinline__ void tap_scalar(const float4& wn, const float4& c,
                                           float& acc) {
    float d0 = wn.x - c.x, d1 = wn.y - c.y, d2 = wn.z - c.z;
    float s = fmaf(d0, d0, fmaf(d1, d1, d2 * d2));
    float e = __builtin_amdgcn_exp2f(-s);   // raw v_exp_f32
    acc = fmaf(e, fabsf(wn.w - c.w), acc);
}

// Separable 5x5 dil-ero mask for 4 x-adjacent pixels.
template <bool INTERIOR>
__device__ __forceinline__ void compute_mask4(const float4* __restrict__ tile,
                                              int ty, int px0, int gy, int gx0,
                                              float* mask) {
    float cmx[8], cmn[8];
    #pragma unroll
    for (int j = 0; j < 8; ++j) {
        int col = px0 + 3 + j;  // tile x of (gx0 - 2 + j)
        float mx = 0.f, mn = 1.f;
        #pragma unroll
        for (int r = 0; r < 5; ++r) {
            float l = (tile[(ty + 3 + r) * LSTRIDE + col].w > 0.5f) ? 1.f : 0.f;
            mx = fmaxf(mx, l);
            if (INTERIOR) {
                mn = fminf(mn, l);
            } else {
                bool rowv = (unsigned)(gy - 2 + r) < (unsigned)HH;
                mn = fminf(mn, rowv ? l : 1.f);
            }
        }
        cmx[j] = mx;
        if (INTERIOR) {
            cmn[j] = mn;
        } else {
            bool colv = (unsigned)(gx0 - 2 + j) < (unsigned)WW;
            cmn[j] = colv ? mn : 1.f;
        }
    }
    #pragma unroll
    for (int k = 0; k < 4; ++k) {
        float mx = cmx[k], mn = cmn[k];
        #pragma unroll
        for (int j2 = 1; j2 < 5; ++j2) {
            mx = fmaxf(mx, cmx[k + j2]);
            mn = fminf(mn, cmn[k + j2]);
        }
        mask[k] = mx - mn;  // 0 or 1
    }
}

__global__ __launch_bounds__(256, 4)
void btm_loss_kernel(const float* __restrict__ pred,
                     const float* __restrict__ feat,
                     float2* __restrict__ partials) {
    __shared__ float4 tile[LH * LSTRIDE];  // 18*43*16B = 12.1 KB
    __shared__ float4 xch[192];            // 3 groups hand partials to group 0
    __shared__ float2 wred[4];

    int bid = blockIdx.x;
    int tx_blk = bid % TILES_X;
    int ty_blk = (bid / TILES_X) % TILES_Y;
    int n = bid / (TILES_X * TILES_Y);

    const int x0 = tx_blk * TX;
    const int y0 = ty_blk * TY;

    const size_t plane = (size_t)HH * WW;
    const float* fr = feat + ((size_t)n * 3 + 0) * plane;
    const float* fg = feat + ((size_t)n * 3 + 1) * plane;
    const float* fb = feat + ((size_t)n * 3 + 2) * plane;
    const float* ps = pred + (size_t)n * plane;

    // ---- stage tile (zero-padded halo, matching jnp.pad; rgb pre-scaled) ----
    for (int i = threadIdx.x; i < LH * LW; i += 256) {
        int lr = i / LW;
        int lc = i - lr * LW;
        int gy = y0 + lr - RAD;
        int gx = x0 + lc - RAD;
        float4 v = make_float4(0.f, 0.f, 0.f, 0.f);
        if ((unsigned)gy < (unsigned)HH && (unsigned)gx < (unsigned)WW) {
            int gi = gy * WW + gx;
            v.x = fr[gi] * RGB_SCALE;
            v.y = fg[gi] * RGB_SCALE;
            v.z = fb[gi] * RGB_SCALE;
            v.w = ps[gi];
        }
        tile[lr * LSTRIDE + lc] = v;
    }
    __syncthreads();

    // 4 wave groups split the 11 dy rows (3/3/3/2); each thread owns 4 px of
    // the 32x8 tile.
    const int t   = threadIdx.x;
    const int g   = t >> 6;      // wave id: dy group (wave-uniform)
    const int tl  = t & 63;
    const int txq = tl & 7;      // 0..7 (x group)
    const int ty  = tl >> 3;     // 0..7 (row)
    const int px0 = txq * 4;

    float4 c0 = tile[(ty + RAD) * LSTRIDE + (px0 + 0 + RAD)];
    float4 c1 = tile[(ty + RAD) * LSTRIDE + (px0 + 1 + RAD)];
    float4 c2 = tile[(ty + RAD) * LSTRIDE + (px0 + 2 + RAD)];
    float4 c3 = tile[(ty + RAD) * LSTRIDE + (px0 + 3 + RAD)];

    // packed center pairs
    f32x2 c01x = {c0.x, c1.x}, c01y = {c0.y, c1.y}, c01z = {c0.z, c1.z}, c01w = {c0.w, c1.w};
    f32x2 c23x = {c2.x, c3.x}, c23y = {c2.y, c3.y}, c23z = {c2.z, c3.z}, c23w = {c2.w, c3.w};

    float acc0 = 0.f, acc1 = 0.f, acc2 = 0.f, acc3 = 0.f;

    const int dy_lo = 3 * g;                    // 0,3,6,9
    const int dy_hi = (g == 3) ? 11 : 3 * g + 3;
    for (int dy = dy_lo; dy < dy_hi; ++dy) {
        const float4* row = &tile[(ty + dy) * LSTRIDE + px0];
        float4 wv[14];
        #pragma unroll
        for (int j = 0; j < 14; ++j) wv[j] = row[j];

        // edge taps (pair halves with non-overlapping valid ranges)
        tap_scalar(wv[0],  c0, acc0);   // c0: dx=0
        tap_scalar(wv[11], c1, acc1);   // c1: dx=10
        tap_scalar(wv[2],  c2, acc2);   // c2: dx=0
        tap_scalar(wv[13], c3, acc3);   // c3: dx=10

        #pragma unroll
        for (int j = 1; j <= 10; ++j)
            tap_pair(wv[j].x, wv[j].y, wv[j].z, wv[j].w,
                     c01x, c01y, c01z, c01w, acc0, acc1);
        #pragma unroll
        for (int j = 3; j <= 12; ++j)
            tap_pair(wv[j].x, wv[j].y, wv[j].z, wv[j].w,
                     c23x, c23y, c23z, c23w, acc2, acc3);
    }

    // ---- exchange: groups 1..3 hand their partial accs to group 0 ----
    if (g > 0) xch[(g - 1) * 64 + tl] = make_float4(acc0, acc1, acc2, acc3);
    __syncthreads();

    float num = 0.f, den = 0.f;
    if (g == 0) {
        #pragma unroll
        for (int w = 0; w < 3; ++w) {
            float4 o = xch[w * 64 + tl];
            acc0 += o.x; acc1 += o.y; acc2 += o.z; acc3 += o.w;
        }

        const int gy  = y0 + ty;
        const int gx0 = x0 + px0;
        float mask[4];
        bool interior = (tx_blk >= 1) && (tx_blk <= TILES_X - 2) &&
                        (ty_blk >= 1) && (ty_blk <= TILES_Y - 2);
        if (interior) compute_mask4<true >(tile, ty, px0, gy, gx0, mask);
        else          compute_mask4<false>(tile, ty, px0, gy, gx0, mask);

        num = fmaf(mask[0], acc0, fmaf(mask[1], acc1,
              fmaf(mask[2], acc2, mask[3] * acc3)));
        den = ((mask[0] + mask[1]) + (mask[2] + mask[3]));
    }

    // ---- wave reduce -> block reduce -> deterministic partial store ----
    #pragma unroll
    for (int off = 32; off > 0; off >>= 1) {
        num += __shfl_down(num, off, 64);
        den += __shfl_down(den, off, 64);
    }
    int wid  = t >> 6;
    int lane = t & 63;
    if (lane == 0) wred[wid] = make_float2(num, den);
    __syncthreads();
    if (t == 0) {
        // only wave 0 carries nonzero num/den, but sum all for safety
        float2 a = wred[0];
        #pragma unroll
        for (int w = 1; w < 4; ++w) { a.x += wred[w].x; a.y += wred[w].y; }
        partials[bid] = a;
    }
}

__global__ __launch_bounds__(256)
void btm_finalize_kernel(const float2* __restrict__ partials,
                         float* __restrict__ out) {
    __shared__ float2 wred[4];
    float num = 0.f, den = 0.f;
    for (int i = threadIdx.x; i < NBLK; i += 256) {
        float2 p = partials[i];
        num += p.x;
        den += p.y;
    }
    #pragma unroll
    for (int off = 32; off > 0; off >>= 1) {
        num += __shfl_down(num, off, 64);
        den += __shfl_down(den, off, 64);
    }
    int wid  = threadIdx.x >> 6;
    int lane = threadIdx.x & 63;
    if (lane == 0) wred[wid] = make_float2(num, den);
    __syncthreads();
    if (threadIdx.x == 0) {
        float2 a = wred[0];
        #pragma unroll
        for (int w = 1; w < 4; ++w) { a.x += wred[w].x; a.y += wred[w].y; }
        out[0] = a.x / (a.y + 1e-6f);
    }
}

extern "C" void kernel_launch(void* const* d_in, const int* in_sizes, int n_in,
                              void* d_out, int out_size, void* d_ws, size_t ws_size,
                              hipStream_t stream) {
    const float* pred = (const float*)d_in[0];  // (8,1,352,352) fp32
    const float* feat = (const float*)d_in[1];  // (8,3,352,352) fp32
    float* out = (float*)d_out;                 // scalar fp32
    float2* partials = (float2*)d_ws;           // NBLK float2 = 31 KB

    btm_loss_kernel<<<dim3(NBLK), dim3(256), 0, stream>>>(pred, feat, partials);
    btm_finalize_kernel<<<dim3(1), dim3(256), 0, stream>>>(partials, out);
}